// Round 5
// baseline (196.807 us; speedup 1.0000x reference)
//
#include <hip/hip_runtime.h>
#include <math.h>

// SelfNorm: out = (x - mean)*std_w + mean*mean_w  (per (b,c) plane over H*W)
// Algebra: x_norm*(s*std_w) + m*mean_w == x*std_w + m*(mean_w - std_w).
//
// ONE WAVE PER PLANE, ZERO BARRIERS: 3136 = 64 lanes x 49 floats.
// Each lane: 12 float4 (stride 64, coalesced) + 1 tail float (3072+lane).
// Shuffle-xor butterfly reduction (all lanes get result), redundant
// per-lane MLP (weights -> hoisted s_loads), apply from registers, store.
// Waves are fully independent -> continuous memory demand, no phase bursts.

typedef float f32x4 __attribute__((ext_vector_type(4)));

constexpr int N_HW  = 56 * 56;   // 3136 elements per (b,c) plane
constexpr int BLOCK = 256;       // 4 independent waves = 4 planes per block
constexpr float EPS = 1e-5f;

__global__ __launch_bounds__(BLOCK) void selfnorm_kernel(
    const float* __restrict__ x,
    const float* __restrict__ W1m, const float* __restrict__ b1m,
    const float* __restrict__ W2m, const float* __restrict__ b2m,
    const float* __restrict__ W1s, const float* __restrict__ b1s,
    const float* __restrict__ W2s, const float* __restrict__ b2s,
    float* __restrict__ out)
{
    const int tid  = threadIdx.x;
    const int wave = tid >> 6;
    const int lane = tid & 63;
    const int plane = blockIdx.x * 4 + wave;           // 8192 planes total
    const long long base = (long long)plane * N_HW;

    const f32x4* __restrict__ src = (const f32x4*)(x + base);
    f32x4* __restrict__ dst       = (f32x4*)(out + base);

    // ---- 12 vec4 loads + 1 scalar tail, all issued back-to-back ----
    f32x4 r[12];
    #pragma unroll
    for (int k = 0; k < 12; ++k) r[k] = src[lane + 64 * k];
    float rt = x[base + 3072 + lane];                  // floats 3072..3135

    float sum   = rt;
    float sumsq = rt * rt;
    #pragma unroll
    for (int k = 0; k < 12; ++k) {
        sum   += (r[k].x + r[k].y) + (r[k].z + r[k].w);
        sumsq += (r[k].x * r[k].x + r[k].y * r[k].y)
               + (r[k].z * r[k].z + r[k].w * r[k].w);
    }

    // ---- 64-lane butterfly: every lane ends with the full-plane sums ----
    #pragma unroll
    for (int off = 1; off < 64; off <<= 1) {
        sum   += __shfl_xor(sum, off, 64);
        sumsq += __shfl_xor(sumsq, off, 64);
    }

    // ---- stats + both tiny MLPs, redundantly per lane ----
    const float mean = sum * (1.0f / (float)N_HW);
    const float var  = (sumsq - sum * mean) * (1.0f / (float)(N_HW - 1)); // ddof=1
    const float stdv = sqrtf(var + EPS);

    float accm = b2m[0];
    float accs = b2s[0];
    #pragma unroll
    for (int j = 0; j < 16; ++j) {
        float hm = fmaf(W1m[j * 2 + 1], stdv, fmaf(W1m[j * 2], mean, b1m[j]));
        accm = fmaf(W2m[j], fmaxf(hm, 0.f), accm);
        float hs = fmaf(W1s[j * 2 + 1], stdv, fmaf(W1s[j * 2], mean, b1s[j]));
        accs = fmaf(W2s[j], fmaxf(hs, 0.f), accs);
    }
    const float mean_w = 1.0f / (1.0f + expf(-accm));
    const float std_w  = 1.0f / (1.0f + expf(-accs));

    // out = x*std_w + mean*(mean_w - std_w)
    const float a  = std_w;
    const float bb = mean * (mean_w - std_w);

    #pragma unroll
    for (int k = 0; k < 12; ++k) {
        f32x4 o;
        o.x = fmaf(r[k].x, a, bb);
        o.y = fmaf(r[k].y, a, bb);
        o.z = fmaf(r[k].z, a, bb);
        o.w = fmaf(r[k].w, a, bb);
        dst[lane + 64 * k] = o;
    }
    out[base + 3072 + lane] = fmaf(rt, a, bb);
}

extern "C" void kernel_launch(void* const* d_in, const int* in_sizes, int n_in,
                              void* d_out, int out_size, void* d_ws, size_t ws_size,
                              hipStream_t stream) {
    const float* x   = (const float*)d_in[0];
    const float* W1m = (const float*)d_in[1];
    const float* b1m = (const float*)d_in[2];
    const float* W2m = (const float*)d_in[3];
    const float* b2m = (const float*)d_in[4];
    const float* W1s = (const float*)d_in[5];
    const float* b1s = (const float*)d_in[6];
    const float* W2s = (const float*)d_in[7];
    const float* b2s = (const float*)d_in[8];
    float* out = (float*)d_out;

    const int blocks = (32 * 256) / 4;  // 8192 planes / 4 waves per block
    selfnorm_kernel<<<blocks, BLOCK, 0, stream>>>(
        x, W1m, b1m, W2m, b2m, W1s, b1s, W2s, b2s, out);
}